// Round 7
// baseline (1621.490 us; speedup 1.0000x reference)
//
#include <hip/hip_runtime.h>
#include <hip/hip_bf16.h>

constexpr int NB = 4;
constexpr int SEQ = 4096;
constexpr int DIM = 2048;
constexpr int NLAYER = 4;
constexpr int NQH = 16;
constexpr int NKVH = 4;
constexpr int WIN = 512;
constexpr int HDIM = 128;
constexpr int CAPN = 1024;
constexpr int MTOK = NB * CAPN;                 // 4096 latent tokens
constexpr int QKVN = (NQH + 2 * NKVH) * HDIM;  // 3072
constexpr int VOFF = DIM + NKVH * HDIM;        // 2560, start of V cols
constexpr float EPSF = 1.1920928955078125e-07f;

typedef __hip_bfloat16 bf16;
typedef __bf16 b16x8 __attribute__((ext_vector_type(8)));
typedef __bf16 b16x4 __attribute__((ext_vector_type(4)));
typedef float f32x4 __attribute__((ext_vector_type(4)));

#define MFMA16(a, b, c) __builtin_amdgcn_mfma_f32_16x16x32_bf16((a), (b), (c), 0, 0, 0)

__device__ __forceinline__ void gload_lds16(const void* g, void* l) {
  __builtin_amdgcn_global_load_lds((__attribute__((address_space(1))) void*)(void*)g,
                                   (__attribute__((address_space(3))) void*)l, 16, 0, 0);
}

// ---------------- cast f32 -> bf16 ----------------
__global__ __launch_bounds__(256) void cast_kernel(const float* __restrict__ in,
                                                   bf16* __restrict__ out, int n) {
  int i = (blockIdx.x * 256 + threadIdx.x) * 4;
  if (i >= n) return;
  float4 v = *(const float4*)(in + i);
  b16x4 o;
  o[0] = (__bf16)v.x; o[1] = (__bf16)v.y; o[2] = (__bf16)v.z; o[3] = (__bf16)v.w;
  *(b16x4*)((__bf16*)out + i) = o;
}

// ------- cast fc1_w with row interleave: chunk c holds [16 a-rows | 16 gate] -------
__global__ __launch_bounds__(256) void cast_fc1_kernel(const float* __restrict__ in,
                                                       bf16* __restrict__ out) {
  int p = blockIdx.x;
  int chunk = p >> 5, w = p & 31;
  int L = (w < 16) ? (chunk * 16 + w) : (DIM + chunk * 16 + (w - 16));
  const float4* spv = (const float4*)(in + (size_t)L * DIM);
  __bf16* op = (__bf16*)out + (size_t)p * DIM;
  int t = threadIdx.x;
#pragma unroll
  for (int j = 0; j < 2; ++j) {
    float4 v = spv[t + j * 256];
    b16x4 o;
    o[0] = (__bf16)v.x; o[1] = (__bf16)v.y; o[2] = (__bf16)v.z; o[3] = (__bf16)v.w;
    *(b16x4*)(op + (t + j * 256) * 4) = o;
  }
}

// ---------------- router: rw = sigmoid(x @ w^T), all f32 ----------------
__global__ __launch_bounds__(256) void router_kernel(const float* __restrict__ x,
                                                     const float* __restrict__ rwt,
                                                     float* __restrict__ rw_out) {
  int tok = blockIdx.x * 4 + (threadIdx.x >> 6);
  int l = threadIdx.x & 63;
  const float* xr = x + (size_t)tok * DIM;
  float s = 0.f;
  for (int c = l; c < DIM; c += 64) s += xr[c] * rwt[c];
  for (int off = 32; off; off >>= 1) s += __shfl_down(s, off);
  if (l == 0) rw_out[tok] = 1.f / (1.f + expf(-s));
}

// ------- rank count, tiled: block (b, jc, ic) counts chunk-vs-chunk -------
__global__ __launch_bounds__(256) void rankcnt_kernel(const float* __restrict__ rw,
                                                      int* __restrict__ rank) {
  int blk = blockIdx.x;
  int ic = blk & 15, jc = (blk >> 4) & 15, b = blk >> 8;
  __shared__ float4 svi[64];
  int t = threadIdx.x;
  if (t < 64) svi[t] = ((const float4*)(rw + (size_t)b * SEQ + ic * 256))[t];
  __syncthreads();
  int j = jc * 256 + t;
  float vj = rw[(size_t)b * SEQ + j];
  int r = 0;
#pragma unroll 16
  for (int q = 0; q < 64; ++q) {
    float4 v = svi[q];
    int i = ic * 256 + q * 4;
    r += (v.x > vj || (v.x == vj && (i + 0) < j)) ? 1 : 0;
    r += (v.y > vj || (v.y == vj && (i + 1) < j)) ? 1 : 0;
    r += (v.z > vj || (v.z == vj && (i + 2) < j)) ? 1 : 0;
    r += (v.w > vj || (v.w == vj && (i + 3) < j)) ? 1 : 0;
  }
  atomicAdd(&rank[b * SEQ + j], r);
}

// -------- select: compact ascending-index selected; top_w quirk gather;
// also writes the `decisions` output --------
__global__ __launch_bounds__(1024) void select_kernel(const int* __restrict__ rank,
                                                      const float* __restrict__ rw,
                                                      int* __restrict__ idxs,
                                                      float* __restrict__ topw,
                                                      float* __restrict__ dec) {
  int b = blockIdx.x;
  int t = threadIdx.x;
  __shared__ int sr[SEQ];
  __shared__ int scnt[1024];
  for (int i = t; i < SEQ; i += 1024) sr[i] = rank[b * SEQ + i];
  __syncthreads();
  for (int i = t; i < SEQ; i += 1024) dec[(size_t)b * SEQ + i] = (sr[i] < CAPN) ? 1.0f : 0.0f;
  int c = 0;
#pragma unroll
  for (int k = 0; k < 4; ++k) c += (sr[t * 4 + k] < CAPN) ? 1 : 0;
  scnt[t] = c;
  __syncthreads();
  for (int off = 1; off < 1024; off <<= 1) {
    int v = scnt[t];
    int vm = (t >= off) ? scnt[t - off] : 0;
    __syncthreads();
    scnt[t] = v + vm;
    __syncthreads();
  }
  int pos = scnt[t] - c;  // exclusive prefix
  for (int k = 0; k < 4; ++k) {
    int j = t * 4 + k;
    int r = sr[j];
    if (r < CAPN) {
      idxs[b * CAPN + pos] = j;
      topw[b * CAPN + pos] = rw[(size_t)b * SEQ + r];
      pos++;
    }
  }
}

// ---------------- gather selected rows ----------------
__global__ __launch_bounds__(256) void gather_kernel(const float* __restrict__ x,
                                                     const int* __restrict__ idxs,
                                                     float* __restrict__ lat) {
  int tok = blockIdx.x;
  int b = tok >> 10, i = tok & 1023;
  int src = idxs[b * CAPN + i];
  const float4* spv = (const float4*)(x + ((size_t)b * SEQ + src) * DIM);
  float4* dp = (float4*)(lat + (size_t)tok * DIM);
  int t = threadIdx.x;
  dp[t] = spv[t];
  dp[t + 256] = spv[t + 256];
}

// ---------------- RMSNorm (f32 in, bf16 out) ----------------
__global__ __launch_bounds__(256) void rmsnorm_kernel(const float* __restrict__ in,
                                                      const float* __restrict__ w,
                                                      bf16* __restrict__ out) {
  int row = blockIdx.x;
  int t = threadIdx.x;
  const float4* spv = (const float4*)(in + (size_t)row * DIM);
  float4 v0 = spv[t], v1 = spv[t + 256];
  float ss = v0.x * v0.x + v0.y * v0.y + v0.z * v0.z + v0.w * v0.w +
             v1.x * v1.x + v1.y * v1.y + v1.z * v1.z + v1.w * v1.w;
  for (int off = 32; off; off >>= 1) ss += __shfl_down(ss, off);
  __shared__ float red[4];
  if ((t & 63) == 0) red[t >> 6] = ss;
  __syncthreads();
  float total = red[0] + red[1] + red[2] + red[3];
  float sc = rsqrtf(total * (1.0f / DIM) + EPSF);
  const float4* wp = (const float4*)w;
  float4 w0 = wp[t], w1 = wp[t + 256];
  __bf16* op = (__bf16*)out + (size_t)row * DIM;
  b16x4 o0, o1;
  o0[0] = (__bf16)(v0.x * w0.x * sc); o0[1] = (__bf16)(v0.y * w0.y * sc);
  o0[2] = (__bf16)(v0.z * w0.z * sc); o0[3] = (__bf16)(v0.w * w0.w * sc);
  o1[0] = (__bf16)(v1.x * w1.x * sc); o1[1] = (__bf16)(v1.y * w1.y * sc);
  o1[2] = (__bf16)(v1.z * w1.z * sc); o1[3] = (__bf16)(v1.w * w1.w * sc);
  *(b16x4*)(op + t * 4) = o0;
  *(b16x4*)(op + 1024 + t * 4) = o1;
}

// ============ 8-phase 256x256 GEMM, m201-smooth: C = A @ Bw^T ============
// BK=64, dbuf A/B 256x64 tiles (128 KB), 512 thr (8 waves 2Mx4N), per-wave
// C = 128x64. EVERY phase stages exactly ONE half-tile (128rows x 64cols,
// 2 gloads/thread) -> constant 2..6 halves in flight (smooth streaming).
// Phase: {ds-read quadrant frags | stage 1 half -> BAR -> setprio 16 MFMA
// -> BAR}. vmcnt(4) at P4/P8 only.
// Stage ledger (iter i, t0=2i, t1=2i+1; buf0=t0, buf1=t1):
//   P1: A.h0(t1)->buf1  (buf1.A certified prev-P7-end)
//   P2: A.h1(t1)->buf1
//   P3: B.h0(t0+2)->buf0 (buf0.B reads P1/P2, certified P2-end)
//   P4: B.h1(t0+2)->buf0 ; vmcnt(4) drains [B(t1)@prevP7/P8, A(t1)@P1/P2]
//        -> tile t1 resident before P5; leaves B(t0+2) in flight.
//   P5: A.h0(t0+2)->buf0 (buf0.A reads P1/P3, certified P3-end)
//   P6: A.h1(t0+2)->buf0
//   P7: B.h0(t0+3)->buf1 (buf1.B reads P5/P6, certified P6-end)
//   P8: B.h1(t0+3)->buf1 ; vmcnt(4) drains [B(t0+2), A(t0+2)] -> tile t0+2
//        resident before next P1; leaves B(t0+3) (= invariant entering P1).
// LDS swizzle c^=(row&7)<<4 bytes: linear gload dest + pre-swizzled src.

__device__ __forceinline__ void stage_h(const bf16* g, int K, int kt, int h,
                                        bf16* tile, int tid) {
#pragma unroll
  for (int j = 0; j < 2; ++j) {
    int q = h * 16384 + j * 8192 + tid * 16;  // byte offset in 32KB tile (linear)
    int row = q >> 7;
    int sc = ((tid & 7) ^ (row & 7)) << 3;    // inverse-swizzled source col (elems)
    gload_lds16((const __bf16*)g + (size_t)row * K + kt * 64 + sc,
                (char*)tile + q);
  }
}

__device__ __forceinline__ b16x8 frag8(const bf16* buf, int row, int ks, int hi) {
  int co = (ks * 32 + hi * 8) ^ ((row & 7) << 3);  // swizzled col (elems)
  return *(const b16x8*)((const __bf16*)buf + row * 64 + co);
}

template <bool VT, bool SWI>
__global__ __launch_bounds__(512) void gemm8p(const bf16* __restrict__ A,
                                              const bf16* __restrict__ Bw,
                                              bf16* __restrict__ Cb,
                                              bf16* __restrict__ vTout,
                                              int N, int K, int nbn) {
  __shared__ __align__(16) bf16 sA[2][256 * 64];
  __shared__ __align__(16) bf16 sB[2][256 * 64];
  const int tid = threadIdx.x;
  const int w = tid >> 6, l = tid & 63;
  const int lo = l & 15, hi = l >> 4;
  const int wm = w >> 2, wn = w & 3;
  const int nwg = gridDim.x;
  int bid = blockIdx.x;
  bid = (bid & 7) * (nwg >> 3) + (bid >> 3);  // T1 XCD swizzle (nwg%8==0)
  const int bm = bid / nbn, bn = bid % nbn;
  const bf16* Ab = A + (size_t)bm * 256 * K;
  const bf16* Bb = Bw + (size_t)bn * 256 * K;
  const int nt = K >> 6;       // K=2048 -> 32 (even)
  const int niter = nt >> 1;

  f32x4 acc[8][4];
#pragma unroll
  for (int i = 0; i < 8; ++i)
#pragma unroll
    for (int j = 0; j < 4; ++j) acc[i][j] = f32x4{0.f, 0.f, 0.f, 0.f};

#define LDA_Q(BUF, QM, AF)                                                  \
  do {                                                                      \
    _Pragma("unroll") for (int mi = 0; mi < 4; ++mi)                        \
        _Pragma("unroll") for (int ks = 0; ks < 2; ++ks)                    \
            AF[mi][ks] = frag8((BUF), wm * 128 + (QM)*64 + mi * 16 + lo, ks, hi); \
  } while (0)
#define LDB_Q(BUF, QN, DST)                                                 \
  do {                                                                      \
    _Pragma("unroll") for (int ni = 0; ni < 2; ++ni)                        \
        _Pragma("unroll") for (int ks = 0; ks < 2; ++ks)                    \
            DST[ni][ks] = frag8((BUF), wn * 64 + (QN)*32 + ni * 16 + lo, ks, hi); \
  } while (0)
#define MM_Q(QM, QN, AF, BF)                                                \
  do {                                                                      \
    __builtin_amdgcn_s_setprio(1);                                          \
    _Pragma("unroll") for (int ks = 0; ks < 2; ++ks)                        \
        _Pragma("unroll") for (int mi = 0; mi < 4; ++mi)                    \
            _Pragma("unroll") for (int ni = 0; ni < 2; ++ni)                \
                acc[(QM)*4 + mi][(QN)*2 + ni] =                             \
                    MFMA16(AF[mi][ks], BF[ni][ks], acc[(QM)*4 + mi][(QN)*2 + ni]); \
    __builtin_amdgcn_s_setprio(0);                                          \
  } while (0)
#define BAR() __builtin_amdgcn_s_barrier()

  // prologue: A(0),B(0),B(1) staged (6 halves); vmcnt(4) drains tile0,
  // leaving B(1) (2 halves) = steady-state invariant entering P1.
  stage_h(Ab, K, 0, 0, sA[0], tid);
  stage_h(Ab, K, 0, 1, sA[0], tid);
  stage_h(Bb, K, 0, 0, sB[0], tid);
  stage_h(Bb, K, 0, 1, sB[0], tid);
  stage_h(Bb, K, 1, 0, sB[1], tid);
  stage_h(Bb, K, 1, 1, sB[1], tid);
  asm volatile("s_waitcnt vmcnt(4)" ::: "memory");
  __builtin_amdgcn_sched_barrier(0);
  BAR();

  for (int i = 0; i < niter; ++i) {
    const int t0 = 2 * i;
    const bool s2 = (t0 + 2) < nt;
    b16x8 af0[4][2], af1[4][2], bf0[2][2], bf1[2][2];
    // P1
    LDA_Q(sA[0], 0, af0); LDB_Q(sB[0], 0, bf0);
    stage_h(Ab, K, t0 + 1, 0, sA[1], tid);
    BAR(); MM_Q(0, 0, af0, bf0); BAR();
    // P2
    LDB_Q(sB[0], 1, bf1);
    stage_h(Ab, K, t0 + 1, 1, sA[1], tid);
    BAR(); MM_Q(0, 1, af0, bf1); BAR();
    // P3
    LDA_Q(sA[0], 1, af1);
    if (s2) stage_h(Bb, K, t0 + 2, 0, sB[0], tid);
    BAR(); MM_Q(1, 0, af1, bf0); BAR();
    // P4
    if (s2) stage_h(Bb, K, t0 + 2, 1, sB[0], tid);
    BAR(); MM_Q(1, 1, af1, bf1);
    if (s2) asm volatile("s_waitcnt vmcnt(4)" ::: "memory");
    else    asm volatile("s_waitcnt vmcnt(0)" ::: "memory");
    __builtin_amdgcn_sched_barrier(0);
    BAR();
    // P5
    LDA_Q(sA[1], 0, af0); LDB_Q(sB[1], 0, bf0);
    if (s2) stage_h(Ab, K, t0 + 2, 0, sA[0], tid);
    BAR(); MM_Q(0, 0, af0, bf0); BAR();
    // P6
    LDB_Q(sB[1], 1, bf1);
    if (s2) stage_h(Ab, K, t0 + 2, 1, sA[0], tid);
    BAR(); MM_Q(0, 1, af0, bf1); BAR();
    // P7
    LDA_Q(sA[1], 1, af1);
    if (s2) stage_h(Bb, K, t0 + 3, 0, sB[1], tid);
    BAR(); MM_Q(1, 0, af1, bf0); BAR();
    // P8
    if (s2) stage_h(Bb, K, t0 + 3, 1, sB[1], tid);
    BAR(); MM_Q(1, 1, af1, bf1);
    if (s2) {
      asm volatile("s_waitcnt vmcnt(4)" ::: "memory");
      __builtin_amdgcn_sched_barrier(0);
    }
    BAR();
  }
#undef LDA_Q
#undef LDB_Q
#undef MM_Q
#undef BAR

  // epilogue
  if constexpr (SWI) {
    // fused SwiGLU: fj even = a, fj odd = gate (same logical col, same lane)
#pragma unroll
    for (int fi = 0; fi < 8; ++fi) {
      int row0 = bm * 256 + wm * 128 + fi * 16 + hi * 4;
#pragma unroll
      for (int j2 = 0; j2 < 2; ++j2) {
        int colL = bn * 128 + wn * 32 + j2 * 16 + lo;  // logical col in [0,2048)
#pragma unroll
        for (int r = 0; r < 4; ++r) {
          float a = acc[fi][2 * j2][r];
          float g = acc[fi][2 * j2 + 1][r];
          float s = g / (1.f + __expf(-g));
          Cb[(size_t)(row0 + r) * DIM + colL] = __float2bfloat16(a * s);
        }
      }
    }
  } else {
#pragma unroll
    for (int fi = 0; fi < 8; ++fi) {
      int row0 = bm * 256 + wm * 128 + fi * 16 + hi * 4;
#pragma unroll
      for (int fj = 0; fj < 4; ++fj) {
        int col = bn * 256 + wn * 64 + fj * 16 + lo;
#pragma unroll
        for (int r = 0; r < 4; ++r) {
          bf16 bv = __float2bfloat16(acc[fi][fj][r]);
          Cb[(size_t)(row0 + r) * N + col] = bv;
          if constexpr (VT) {
            if (col >= VOFF) {
              int cc = col - VOFF;
              int kvh = cc >> 7, d = cc & 127;
              int row = row0 + r;
              int bb = row >> 10, tk = row & 1023;
              vTout[((size_t)(bb * NKVH + kvh) * HDIM + d) * CAPN + tk] = bv;
            }
          }
        }
      }
    }
  }
}

// ========== R3 pipelined GEMM kept for N=2048 shapes (proj/fc2) ==========
template <int ROWS>
__device__ __forceinline__ void stage_tile(const bf16* gbase, int ldk, int kt,
                                           bf16* lbuf, int tid) {
#pragma unroll
  for (int i = 0; i < ROWS / 128; ++i) {
    int q = i * 8192 + tid * 16;
    int row = q >> 6;
    int ce = ((tid & 3) ^ ((row >> 1) & 3)) << 3;
    gload_lds16((const __bf16*)gbase + (size_t)row * ldk + kt * 32 + ce,
                (char*)lbuf + q);
  }
}

__device__ __forceinline__ b16x8 frag_ld(const bf16* buf, int row, int hi) {
  int ce = (hi ^ ((row >> 1) & 3)) << 3;
  return *(const b16x8*)((const __bf16*)buf + row * 32 + ce);
}

template <int MR, bool ADD, bool OUTBF>
__global__ __launch_bounds__(512, 2) void gemm256(const bf16* __restrict__ A,
                                                  const bf16* __restrict__ Bw,
                                                  float* __restrict__ Cf,
                                                  bf16* __restrict__ Cb,
                                                  int N, int K, int nbn) {
  constexpr int BM = MR * 32;
  constexpr int PH = MR / 4;
  __shared__ __align__(16) bf16 sA[4][BM * 32];
  __shared__ __align__(16) bf16 sB[4][256 * 32];
  const int tid = threadIdx.x;
  const int w = tid >> 6, l = tid & 63;
  const int lo = l & 15, hi = l >> 4;
  const int wm = w >> 2, wn = w & 3;
  const int nwg = gridDim.x;
  int bid = blockIdx.x;
  bid = (bid & 7) * (nwg >> 3) + (bid >> 3);
  const int bm = bid / nbn, bn = bid % nbn;
  const bf16* Ab = A + (size_t)bm * BM * K;
  const bf16* Bb = Bw + (size_t)bn * 256 * K;
  const int nt = K >> 5;

  f32x4 acc[MR][4];
#pragma unroll
  for (int i = 0; i < MR; ++i)
#pragma unroll
    for (int j = 0; j < 4; ++j) acc[i][j] = f32x4{0.f, 0.f, 0.f, 0.f};

  for (int tt = 0; tt < 3; ++tt) {
    stage_tile<BM>(Ab, K, tt, sA[tt], tid);
    stage_tile<256>(Bb, K, tt, sB[tt], tid);
  }
  if constexpr (MR == 8) asm volatile("s_waitcnt vmcnt(8)" ::: "memory");
  else                   asm volatile("s_waitcnt vmcnt(6)" ::: "memory");
  __builtin_amdgcn_sched_barrier(0);
  __builtin_amdgcn_s_barrier();

  for (int t = 0; t < nt; ++t) {
    const bf16* bufA = sA[t & 3];
    const bf16* bufB = sB[t & 3];
    b16x8 bfr[4];
#pragma unroll
    for (int p = 0; p < PH; ++p) {
      b16x8 af[4];
#pragma unroll
      for (int mi = 0; mi < 4; ++mi)
        af[mi] = frag_ld(bufA, wm * (MR * 16) + p * 64 + mi * 16 + lo, hi);
      if (p == 0) {
#pragma unroll
        for (int ni = 0; ni < 4; ++ni)
          bfr[ni] = frag_ld(bufB, wn * 64 + ni * 16 + lo, hi);
      }
      if (t + 3 < nt) {
        if (p == 0) stage_tile<BM>(Ab, K, t + 3, sA[(t + 3) & 3], tid);
        if (p == PH - 1) stage_tile<256>(Bb, K, t + 3, sB[(t + 3) & 3], tid);
      }
      __builtin_amdgcn_s_barrier();
      __builtin_amdgcn_s_setprio(1);
#pragma unroll
      for (int mi = 0; mi < 4; ++mi)
#pragma unroll
        for (int ni = 0; ni < 4; ++ni)
          acc[p * 4 + mi][ni] = MFMA16(af[mi], bfr[ni], acc[p * 4 + mi][ni]);
      __builtin_amdgcn_s_setprio(0);
      if (p == PH - 1) {
        if (t + 3 < nt) {
          if constexpr (MR == 8) asm volatile("s_waitcnt vmcnt(8)" ::: "memory");
          else                   asm volatile("s_waitcnt vmcnt(6)" ::: "memory");
        } else if (t + 2 < nt) {
          if constexpr (MR == 8) asm volatile("s_waitcnt vmcnt(4)" ::: "memory");
          else                   asm volatile("s_waitcnt vmcnt(3)" ::: "memory");
        } else if (t + 1 < nt) {
          asm volatile("s_waitcnt vmcnt(0)" ::: "memory");
        }
        __builtin_amdgcn_sched_barrier(0);
      }
      __builtin_amdgcn_s_barrier();
    }
  }

#pragma unroll
  for (int mi = 0; mi < MR; ++mi) {
    int row0 = bm * BM + wm * (MR * 16) + mi * 16 + hi * 4;
#pragma unroll
    for (int ni = 0; ni < 4; ++ni) {
      int col = bn * 256 + wn * 64 + ni * 16 + lo;
#pragma unroll
      for (int r = 0; r < 4; ++r) {
        size_t idx = (size_t)(row0 + r) * N + col;
        float v = acc[mi][ni][r];
        if constexpr (ADD) v += Cf[idx];
        if constexpr (OUTBF) {
          Cb[idx] = __float2bfloat16(v);
        } else {
          Cf[idx] = v;
        }
      }
    }
  }
}

// ------------- GQA attention: causal 512-window + ALiBi, flash-style -------------
__global__ __launch_bounds__(256) void attn_kernel(const bf16* __restrict__ qkvb,
                                                   const bf16* __restrict__ vT,
                                                   bf16* __restrict__ attb) {
  const int blk = blockIdx.x;
  const int qc = blk & 31;
  const int kvh = (blk >> 5) & 3;
  const int b = blk >> 7;
  const int w = threadIdx.x >> 6, l = threadIdx.x & 63;
  const int lo = l & 15, hi = l >> 4;
  const int h = kvh * 4 + w;
  const float slope = exp2f(-0.5f * (float)(h + 1));
  const float scale = 0.08838834764831845f;  // 1/sqrt(128)
  __shared__ __align__(16) bf16 p_lds[4][2][16 * 32];
  const __bf16* qp = (const __bf16*)qkvb;
  const __bf16* vtp = (const __bf16*)vT + (size_t)(b * NKVH + kvh) * HDIM * CAPN;
  const size_t tb = (size_t)b * CAPN;
  const int i0b = qc * 32;

  b16x8 aq[2][4];
#pragma unroll
  for (int qt = 0; qt < 2; ++qt) {
    const __bf16* qrow = qp + (tb + i0b + qt * 16 + lo) * QKVN + h * HDIM + hi * 8;
#pragma unroll
    for (int c = 0; c < 4; ++c) aq[qt][c] = *(const b16x8*)(qrow + c * 32);
  }

  f32x4 acc[2][8];
#pragma unroll
  for (int qt = 0; qt < 2; ++qt)
#pragma unroll
    for (int d = 0; d < 8; ++d) acc[qt][d] = f32x4{0.f, 0.f, 0.f, 0.f};
  float mrow[2][4], ssum[2][4];
#pragma unroll
  for (int qt = 0; qt < 2; ++qt)
#pragma unroll
    for (int r = 0; r < 4; ++r) { mrow[qt][r] = -1e30f; ssum[qt][r] = 0.f; }

  int jlo = i0b - WIN;
  if (jlo < 0) jlo = 0;
  jlo &= ~31;
  for (int j0 = jlo; j0 <= i0b; j0 += 32) {
    b16x8 kf[2][4];
#pragma unroll
    for (int jt = 0; jt < 2; ++jt) {
      const __bf16* krow = qp + (tb + j0 + jt * 16 + lo) * QKVN + DIM + kvh * HDIM + hi * 8;
#pragma unroll
      for (int c = 0; c < 4; ++c) kf[jt][c] = *(const b16x8*)(krow + c * 32);
    }
    f32x4 s[2][2];
#pragma unroll
    for (int qt = 0; qt < 2; ++qt)
#pragma unroll
      for (int jt = 0; jt < 2; ++jt) {
        s[qt][jt] = f32x4{0.f, 0.f, 0.f, 0.f};
#pragma unroll
        for (int c = 0; c < 4; ++c) s[qt][jt] = MFMA16(aq[qt][c], kf[jt][c], s[qt][jt]);
      }
#pragma unroll
    for (int qt = 0; qt < 2; ++qt) {
#pragma unroll
      for (int r = 0; r < 4; ++r) {
        const int i = i0b + qt * 16 + hi * 4 + r;
        float d0f = (float)(i - (j0 + lo));
        float d1f = (float)(i - (j0 + 16 + lo));
        float v0 = (d0f >= 0.f && d0f <= 512.f) ? (s[qt][0][r] * scale - slope * d0f) : -1e30f;
        float v1 = (d1f >= 0.f && d1f <= 512.f) ? (s[qt][1][r] * scale - slope * d1f) : -1e30f;
        float tm = fmaxf(v0, v1);
#pragma unroll
        for (int off = 1; off < 16; off <<= 1) tm = fmaxf(tm, __shfl_xor(tm, off));
        float mnew = fmaxf(mrow[qt][r], tm);
        float e0 = (v0 > -1e29f) ? __expf(v0 - mnew) : 0.f;
        float e1 = (v1 > -1e29f) ? __expf(v1 - mnew) : 0.f;
        float rs = e0 + e1;
#pragma unroll
        for (int off = 1; off < 16; off <<= 1) rs += __shfl_xor(rs, off);
        float corr = (mrow[qt][r] > -1e29f) ? __expf(mrow[qt][r] - mnew) : 0.f;
        ssum[qt][r] = ssum[qt][r] * corr + rs;
        mrow[qt][r] = mnew;
#pragma unroll
        for (int d = 0; d < 8; ++d) acc[qt][d][r] *= corr;
        p_lds[w][qt][(hi * 4 + r) * 32 + lo] = __float2bfloat16(e0);
        p_lds[w][qt][(hi * 4 + r) * 32 + 16 + lo] = __float2bfloat16(e1);
      }
    }
    b16x8 pa[2];
    pa[0] = *(const b16x8*)((const __bf16*)p_lds[w][0] + lo * 32 + hi * 8);
    pa[1] = *(const b16x8*)((const __bf16*)p_lds[w][1] + lo * 32 + hi * 8);
#pragma unroll
    for (int dh = 0; dh < 2; ++dh) {
      b16x8 bv[4];
#pragma unroll
      for (int dd = 0; dd < 4; ++dd) {
        int d = dh * 4 + dd;
        bv[dd] = *(const b16x8*)(vtp + (size_t)(d * 16 + lo) * CAPN + j0 + hi * 8);
      }
#pragma unroll
      for (int qt = 0; qt < 2; ++qt)
#pragma unroll
        for (int dd = 0; dd < 4; ++dd)
          acc[qt][dh * 4 + dd] = MFMA16(pa[qt], bv[dd], acc[qt][dh * 4 + dd]);
    }
  }
#pragma unroll
  for (int qt = 0; qt < 2; ++qt)
#pragma unroll
    for (int d = 0; d < 8; ++d)
#pragma unroll
      for (int r = 0; r < 4; ++r) {
        int row = i0b + qt * 16 + hi * 4 + r;
        attb[(tb + row) * DIM + h * HDIM + d * 16 + lo] =
            __float2bfloat16(acc[qt][d][r] / ssum[qt][r]);
      }
}

// ---------------- scale by top_w and scatter into pred ----------------
__global__ __launch_bounds__(256) void scatter_kernel(const float* __restrict__ lat,
                                                      const int* __restrict__ idxs,
                                                      const float* __restrict__ topw,
                                                      float* __restrict__ pred) {
  int tok = blockIdx.x;
  int b = tok >> 10, i = tok & 1023;
  int dst = idxs[b * CAPN + i];
  float wv = topw[b * CAPN + i];
  const float4* spv = (const float4*)(lat + (size_t)tok * DIM);
  float4* dp = (float4*)(pred + ((size_t)b * SEQ + dst) * DIM);
  int t = threadIdx.x;
  float4 v = spv[t];
  v.x *= wv; v.y *= wv; v.z *= wv; v.w *= wv;
  dp[t] = v;
  v = spv[t + 256];
  v.x *= wv; v.y *= wv; v.z *= wv; v.w *= wv;
  dp[t + 256] = v;
}

extern "C" void kernel_launch(void* const* d_in, const int* in_sizes, int n_in,
                              void* d_out, int out_size, void* d_ws, size_t ws_size,
                              hipStream_t stream) {
  const float* x        = (const float*)d_in[0];
  const float* router_w = (const float*)d_in[1];
  const float* norm1_w  = (const float*)d_in[2];
  const float* norm2_w  = (const float*)d_in[3];
  const float* qkv_w    = (const float*)d_in[4];
  const float* proj_w   = (const float*)d_in[5];
  const float* fc1_w    = (const float*)d_in[6];
  const float* fc2_w    = (const float*)d_in[7];

  float* pred   = (float*)d_out;                       // [NB,SEQ,DIM]
  float* rw_out = pred + (size_t)NB * SEQ * DIM;       // [NB,SEQ,1]
  float* dec    = rw_out + (size_t)NB * SEQ;           // [NB,SEQ,1]

  // workspace
  char* ws = (char*)d_ws;
  float* lat  = (float*)ws; ws += (size_t)MTOK * DIM * 4;       // 33.5 MB f32
  bf16* xn    = (bf16*)ws;  ws += (size_t)MTOK * DIM * 2;       // 16.8 MB
  bf16* qkvb  = (bf16*)ws;  ws += (size_t)MTOK * QKVN * 2;      // 25.2 MB
  bf16* attb  = (bf16*)ws;  ws += (size_t)MTOK * DIM * 2;       // 16.8 MB
  int* rank   = (int*)ws;   ws += (size_t)NB * SEQ * 4;
  int* idxs   = (int*)ws;   ws += (size_t)NB * CAPN * 4;
  float* topw = (float*)ws; ws += (size_t)NB * CAPN * 4;

  // scratch inside the pred output region (zeroed only at the very end)
  char* sp = (char*)pred;
  sp += (size_t)MTOK * (2 * DIM) * 2;                          // (hole, unused)
  bf16* wq = (bf16*)sp; sp += (size_t)QKVN * DIM * 2;          // 12.6 MB
  bf16* wp = (bf16*)sp; sp += (size_t)DIM * DIM * 2;           //  8.4 MB
  bf16* w1 = (bf16*)sp; sp += (size_t)(2 * DIM) * DIM * 2;     // 16.8 MB
  bf16* w2 = (bf16*)sp; sp += (size_t)DIM * DIM * 2;           //  8.4 MB
  bf16* vT = (bf16*)sp; sp += (size_t)NB * NKVH * HDIM * CAPN * 2;  // 4.2 MB

  // router + top-k (f32 exact path)
  router_kernel<<<NB * SEQ / 4, 256, 0, stream>>>(x, router_w, rw_out);
  hipMemsetAsync(rank, 0, (size_t)NB * SEQ * 4, stream);
  rankcnt_kernel<<<NB * 256, 256, 0, stream>>>(rw_out, rank);
  select_kernel<<<NB, 1024, 0, stream>>>(rank, rw_out, idxs, topw, dec);
  gather_kernel<<<MTOK, 256, 0, stream>>>(x, idxs, lat);

  for (int l = 0; l < NLAYER; ++l) {
    cast_kernel<<<(QKVN * DIM) / 1024, 256, 0, stream>>>(qkv_w + (size_t)l * QKVN * DIM, wq, QKVN * DIM);
    cast_kernel<<<(DIM * DIM) / 1024, 256, 0, stream>>>(proj_w + (size_t)l * DIM * DIM, wp, DIM * DIM);
    cast_fc1_kernel<<<2 * DIM, 256, 0, stream>>>(fc1_w + (size_t)l * 2 * DIM * DIM, w1);
    cast_kernel<<<(DIM * DIM) / 1024, 256, 0, stream>>>(fc2_w + (size_t)l * DIM * DIM, w2, DIM * DIM);

    rmsnorm_kernel<<<MTOK, 256, 0, stream>>>(lat, norm1_w + (size_t)l * DIM, xn);
    // qkv: M=4096 N=3072 -> 8-phase 256^2: grid 16*12=192
    gemm8p<true, false><<<(MTOK / 256) * (QKVN / 256), 512, 0, stream>>>(
        xn, wq, qkvb, vT, QKVN, DIM, QKVN / 256);
    attn_kernel<<<NB * NKVH * 32, 256, 0, stream>>>(qkvb, vT, attb);
    // proj: N=2048 -> R3 structure: grid 32*8=256
    gemm256<4, true, false><<<(MTOK / 128) * (DIM / 256), 512, 0, stream>>>(
        attb, wp, lat, nullptr, DIM, DIM, DIM / 256);

    rmsnorm_kernel<<<MTOK, 256, 0, stream>>>(lat, norm2_w + (size_t)l * DIM, xn);
    // fc1 + fused SwiGLU: M=4096 N=4096 -> out attb [4096,2048]
    gemm8p<false, true><<<(MTOK / 256) * (2 * DIM / 256), 512, 0, stream>>>(
        xn, w1, attb, nullptr, 2 * DIM, DIM, 2 * DIM / 256);
    // fc2: N=2048 -> R3 structure
    gemm256<4, true, false><<<(MTOK / 128) * (DIM / 256), 512, 0, stream>>>(
        attb, w2, lat, nullptr, DIM, DIM, DIM / 256);
  }

  // finalize outputs: zero pred (erases scratch), then scatter lat * top_w
  hipMemsetAsync(pred, 0, (size_t)NB * SEQ * DIM * 4, stream);
  scatter_kernel<<<MTOK, 256, 0, stream>>>(lat, idxs, topw, pred);
}

// Round 8
// 1498.756 us; speedup vs baseline: 1.0819x; 1.0819x over previous
//
#include <hip/hip_runtime.h>
#include <hip/hip_bf16.h>

constexpr int NB = 4;
constexpr int SEQ = 4096;
constexpr int DIM = 2048;
constexpr int NLAYER = 4;
constexpr int NQH = 16;
constexpr int NKVH = 4;
constexpr int WIN = 512;
constexpr int HDIM = 128;
constexpr int CAPN = 1024;
constexpr int MTOK = NB * CAPN;                 // 4096 latent tokens
constexpr int QKVN = (NQH + 2 * NKVH) * HDIM;  // 3072
constexpr int VOFF = DIM + NKVH * HDIM;        // 2560, start of V cols
constexpr float EPSF = 1.1920928955078125e-07f;

typedef __hip_bfloat16 bf16;
typedef __bf16 b16x8 __attribute__((ext_vector_type(8)));
typedef __bf16 b16x4 __attribute__((ext_vector_type(4)));
typedef float f32x4 __attribute__((ext_vector_type(4)));

#define MFMA16(a, b, c) __builtin_amdgcn_mfma_f32_16x16x32_bf16((a), (b), (c), 0, 0, 0)

__device__ __forceinline__ void gload_lds16(const void* g, void* l) {
  __builtin_amdgcn_global_load_lds((__attribute__((address_space(1))) void*)(void*)g,
                                   (__attribute__((address_space(3))) void*)l, 16, 0, 0);
}

// ---------------- cast f32 -> bf16 ----------------
__global__ __launch_bounds__(256) void cast_kernel(const float* __restrict__ in,
                                                   bf16* __restrict__ out, int n) {
  int i = (blockIdx.x * 256 + threadIdx.x) * 4;
  if (i >= n) return;
  float4 v = *(const float4*)(in + i);
  b16x4 o;
  o[0] = (__bf16)v.x; o[1] = (__bf16)v.y; o[2] = (__bf16)v.z; o[3] = (__bf16)v.w;
  *(b16x4*)((__bf16*)out + i) = o;
}

// ------- cast fc1_w with row interleave: chunk c holds [16 a-rows | 16 gate] -------
__global__ __launch_bounds__(256) void cast_fc1_kernel(const float* __restrict__ in,
                                                       bf16* __restrict__ out) {
  int p = blockIdx.x;
  int chunk = p >> 5, w = p & 31;
  int L = (w < 16) ? (chunk * 16 + w) : (DIM + chunk * 16 + (w - 16));
  const float4* spv = (const float4*)(in + (size_t)L * DIM);
  __bf16* op = (__bf16*)out + (size_t)p * DIM;
  int t = threadIdx.x;
#pragma unroll
  for (int j = 0; j < 2; ++j) {
    float4 v = spv[t + j * 256];
    b16x4 o;
    o[0] = (__bf16)v.x; o[1] = (__bf16)v.y; o[2] = (__bf16)v.z; o[3] = (__bf16)v.w;
    *(b16x4*)(op + (t + j * 256) * 4) = o;
  }
}

// ---------------- router: rw = sigmoid(x @ w^T), all f32 ----------------
__global__ __launch_bounds__(256) void router_kernel(const float* __restrict__ x,
                                                     const float* __restrict__ rwt,
                                                     float* __restrict__ rw_out) {
  int tok = blockIdx.x * 4 + (threadIdx.x >> 6);
  int l = threadIdx.x & 63;
  const float* xr = x + (size_t)tok * DIM;
  float s = 0.f;
  for (int c = l; c < DIM; c += 64) s += xr[c] * rwt[c];
  for (int off = 32; off; off >>= 1) s += __shfl_down(s, off);
  if (l == 0) rw_out[tok] = 1.f / (1.f + expf(-s));
}

// ------- rank count, tiled: block (b, jc, ic) counts chunk-vs-chunk -------
__global__ __launch_bounds__(256) void rankcnt_kernel(const float* __restrict__ rw,
                                                      int* __restrict__ rank) {
  int blk = blockIdx.x;
  int ic = blk & 15, jc = (blk >> 4) & 15, b = blk >> 8;
  __shared__ float4 svi[64];
  int t = threadIdx.x;
  if (t < 64) svi[t] = ((const float4*)(rw + (size_t)b * SEQ + ic * 256))[t];
  __syncthreads();
  int j = jc * 256 + t;
  float vj = rw[(size_t)b * SEQ + j];
  int r = 0;
#pragma unroll 16
  for (int q = 0; q < 64; ++q) {
    float4 v = svi[q];
    int i = ic * 256 + q * 4;
    r += (v.x > vj || (v.x == vj && (i + 0) < j)) ? 1 : 0;
    r += (v.y > vj || (v.y == vj && (i + 1) < j)) ? 1 : 0;
    r += (v.z > vj || (v.z == vj && (i + 2) < j)) ? 1 : 0;
    r += (v.w > vj || (v.w == vj && (i + 3) < j)) ? 1 : 0;
  }
  atomicAdd(&rank[b * SEQ + j], r);
}

// -------- select: compact ascending-index selected; top_w quirk gather;
// also writes the `decisions` output --------
__global__ __launch_bounds__(1024) void select_kernel(const int* __restrict__ rank,
                                                      const float* __restrict__ rw,
                                                      int* __restrict__ idxs,
                                                      float* __restrict__ topw,
                                                      float* __restrict__ dec) {
  int b = blockIdx.x;
  int t = threadIdx.x;
  __shared__ int sr[SEQ];
  __shared__ int scnt[1024];
  for (int i = t; i < SEQ; i += 1024) sr[i] = rank[b * SEQ + i];
  __syncthreads();
  for (int i = t; i < SEQ; i += 1024) dec[(size_t)b * SEQ + i] = (sr[i] < CAPN) ? 1.0f : 0.0f;
  int c = 0;
#pragma unroll
  for (int k = 0; k < 4; ++k) c += (sr[t * 4 + k] < CAPN) ? 1 : 0;
  scnt[t] = c;
  __syncthreads();
  for (int off = 1; off < 1024; off <<= 1) {
    int v = scnt[t];
    int vm = (t >= off) ? scnt[t - off] : 0;
    __syncthreads();
    scnt[t] = v + vm;
    __syncthreads();
  }
  int pos = scnt[t] - c;  // exclusive prefix
  for (int k = 0; k < 4; ++k) {
    int j = t * 4 + k;
    int r = sr[j];
    if (r < CAPN) {
      idxs[b * CAPN + pos] = j;
      topw[b * CAPN + pos] = rw[(size_t)b * SEQ + r];
      pos++;
    }
  }
}

// ---------------- gather selected rows ----------------
__global__ __launch_bounds__(256) void gather_kernel(const float* __restrict__ x,
                                                     const int* __restrict__ idxs,
                                                     float* __restrict__ lat) {
  int tok = blockIdx.x;
  int b = tok >> 10, i = tok & 1023;
  int src = idxs[b * CAPN + i];
  const float4* spv = (const float4*)(x + ((size_t)b * SEQ + src) * DIM);
  float4* dp = (float4*)(lat + (size_t)tok * DIM);
  int t = threadIdx.x;
  dp[t] = spv[t];
  dp[t + 256] = spv[t + 256];
}

// ---------------- RMSNorm (f32 in, bf16 out) ----------------
__global__ __launch_bounds__(256) void rmsnorm_kernel(const float* __restrict__ in,
                                                      const float* __restrict__ w,
                                                      bf16* __restrict__ out) {
  int row = blockIdx.x;
  int t = threadIdx.x;
  const float4* spv = (const float4*)(in + (size_t)row * DIM);
  float4 v0 = spv[t], v1 = spv[t + 256];
  float ss = v0.x * v0.x + v0.y * v0.y + v0.z * v0.z + v0.w * v0.w +
             v1.x * v1.x + v1.y * v1.y + v1.z * v1.z + v1.w * v1.w;
  for (int off = 32; off; off >>= 1) ss += __shfl_down(ss, off);
  __shared__ float red[4];
  if ((t & 63) == 0) red[t >> 6] = ss;
  __syncthreads();
  float total = red[0] + red[1] + red[2] + red[3];
  float sc = rsqrtf(total * (1.0f / DIM) + EPSF);
  const float4* wp = (const float4*)w;
  float4 w0 = wp[t], w1 = wp[t + 256];
  __bf16* op = (__bf16*)out + (size_t)row * DIM;
  b16x4 o0, o1;
  o0[0] = (__bf16)(v0.x * w0.x * sc); o0[1] = (__bf16)(v0.y * w0.y * sc);
  o0[2] = (__bf16)(v0.z * w0.z * sc); o0[3] = (__bf16)(v0.w * w0.w * sc);
  o1[0] = (__bf16)(v1.x * w1.x * sc); o1[1] = (__bf16)(v1.y * w1.y * sc);
  o1[2] = (__bf16)(v1.z * w1.z * sc); o1[3] = (__bf16)(v1.w * w1.w * sc);
  *(b16x4*)(op + t * 4) = o0;
  *(b16x4*)(op + 1024 + t * 4) = o1;
}

// ============ m97-structure GEMM: 128x128 tile, BK=64, single-buffer ============
// 256 thr (4 waves 2x2), wave out 64x64 (4x4 frags), LDS 32 KB -> 3 blocks/CU
// (__launch_bounds__(256,3)). Mechanism: CROSS-BLOCK overlap (m114) — while one
// block drains stage+vmcnt at __syncthreads, co-resident blocks issue MFMA.
// LDS XOR swizzle c^=(row&7)<<4 bytes (linear gload dest + pre-swizzled src).
// MODE: 0 = bf16 out; 1 = bf16 out + vT side-write; 2 = fused SwiGLU -> bf16
// (interleaved w1: 32-row chunks [16 a | 16 gate], out 64 logical cols/tile);
// 3 = f32 residual add (Cf += A@B^T).

__device__ __forceinline__ void stage97(const bf16* g, int K, int kt,
                                        bf16* tile, int tid) {
#pragma unroll
  for (int j = 0; j < 4; ++j) {
    int q = j * 4096 + tid * 16;              // byte offset in 16KB tile (linear)
    int row = q >> 7;                          // 128 B per row (64 cols bf16)
    int sc = ((tid & 7) ^ (row & 7)) << 3;     // inverse-swizzled source col (elems)
    gload_lds16((const __bf16*)g + (size_t)row * K + kt * 64 + sc,
                (char*)tile + q);
  }
}

__device__ __forceinline__ b16x8 frag97(const bf16* buf, int row, int ks, int hi) {
  int co = (ks * 32 + hi * 8) ^ ((row & 7) << 3);  // swizzled col (elems)
  return *(const b16x8*)((const __bf16*)buf + row * 64 + co);
}

template <int MODE>
__global__ __launch_bounds__(256, 3) void gemm97(const bf16* __restrict__ A,
                                                 const bf16* __restrict__ Bw,
                                                 float* __restrict__ Cf,
                                                 bf16* __restrict__ Cb,
                                                 bf16* __restrict__ vTout,
                                                 int N, int K, int nbn) {
  __shared__ __align__(16) bf16 sA[128 * 64];
  __shared__ __align__(16) bf16 sB[128 * 64];
  const int tid = threadIdx.x;
  const int w = tid >> 6, l = tid & 63;
  const int lo = l & 15, hi = l >> 4;
  const int wr = w >> 1, wc = w & 1;
  const int nwg = gridDim.x;
  int bid = blockIdx.x;
  bid = (bid & 7) * (nwg >> 3) + (bid >> 3);  // T1 XCD swizzle (nwg%8==0)
  const int bm = bid / nbn, bn = bid % nbn;
  const bf16* Ab = A + (size_t)bm * 128 * K;
  const bf16* Bb = Bw + (size_t)bn * 128 * K;
  const int nt = K >> 6;

  f32x4 acc[4][4];
#pragma unroll
  for (int i = 0; i < 4; ++i)
#pragma unroll
    for (int j = 0; j < 4; ++j) acc[i][j] = f32x4{0.f, 0.f, 0.f, 0.f};

  for (int t = 0; t < nt; ++t) {
    stage97(Ab, K, t, sA, tid);
    stage97(Bb, K, t, sB, tid);
    __syncthreads();
#pragma unroll
    for (int ks = 0; ks < 2; ++ks) {
      b16x8 af[4], bfm[4];
#pragma unroll
      for (int mi = 0; mi < 4; ++mi)
        af[mi] = frag97(sA, wr * 64 + mi * 16 + lo, ks, hi);
#pragma unroll
      for (int ni = 0; ni < 4; ++ni)
        bfm[ni] = frag97(sB, wc * 64 + ni * 16 + lo, ks, hi);
#pragma unroll
      for (int mi = 0; mi < 4; ++mi)
#pragma unroll
        for (int ni = 0; ni < 4; ++ni)
          acc[mi][ni] = MFMA16(af[mi], bfm[ni], acc[mi][ni]);
    }
    __syncthreads();
  }

  // epilogue
#pragma unroll
  for (int mi = 0; mi < 4; ++mi) {
    int row0 = bm * 128 + wr * 64 + mi * 16 + hi * 4;
    if constexpr (MODE == 2) {
      // fused SwiGLU: fj even = a, fj odd = gate (same logical col, same lane)
#pragma unroll
      for (int j2 = 0; j2 < 2; ++j2) {
        int colL = bn * 64 + wc * 32 + j2 * 16 + lo;  // logical col in [0,2048)
#pragma unroll
        for (int r = 0; r < 4; ++r) {
          float a = acc[mi][2 * j2][r];
          float g = acc[mi][2 * j2 + 1][r];
          float s = g / (1.f + __expf(-g));
          Cb[(size_t)(row0 + r) * DIM + colL] = __float2bfloat16(a * s);
        }
      }
    } else {
#pragma unroll
      for (int ni = 0; ni < 4; ++ni) {
        int col = bn * 128 + wc * 64 + ni * 16 + lo;
#pragma unroll
        for (int r = 0; r < 4; ++r) {
          size_t idx = (size_t)(row0 + r) * N + col;
          float v = acc[mi][ni][r];
          if constexpr (MODE == 3) {
            Cf[idx] += v;
          } else {
            bf16 bv = __float2bfloat16(v);
            Cb[idx] = bv;
            if constexpr (MODE == 1) {
              if (col >= VOFF) {
                int cc = col - VOFF;
                int kvh = cc >> 7, d = cc & 127;
                int row = row0 + r;
                int bb = row >> 10, tk = row & 1023;
                vTout[((size_t)(bb * NKVH + kvh) * HDIM + d) * CAPN + tk] = bv;
              }
            }
          }
        }
      }
    }
  }
}

// ------------- GQA attention: causal 512-window + ALiBi, flash-style -------------
__global__ __launch_bounds__(256) void attn_kernel(const bf16* __restrict__ qkvb,
                                                   const bf16* __restrict__ vT,
                                                   bf16* __restrict__ attb) {
  const int blk = blockIdx.x;
  const int qc = blk & 31;
  const int kvh = (blk >> 5) & 3;
  const int b = blk >> 7;
  const int w = threadIdx.x >> 6, l = threadIdx.x & 63;
  const int lo = l & 15, hi = l >> 4;
  const int h = kvh * 4 + w;
  const float slope = exp2f(-0.5f * (float)(h + 1));
  const float scale = 0.08838834764831845f;  // 1/sqrt(128)
  __shared__ __align__(16) bf16 p_lds[4][2][16 * 32];
  const __bf16* qp = (const __bf16*)qkvb;
  const __bf16* vtp = (const __bf16*)vT + (size_t)(b * NKVH + kvh) * HDIM * CAPN;
  const size_t tb = (size_t)b * CAPN;
  const int i0b = qc * 32;

  b16x8 aq[2][4];
#pragma unroll
  for (int qt = 0; qt < 2; ++qt) {
    const __bf16* qrow = qp + (tb + i0b + qt * 16 + lo) * QKVN + h * HDIM + hi * 8;
#pragma unroll
    for (int c = 0; c < 4; ++c) aq[qt][c] = *(const b16x8*)(qrow + c * 32);
  }

  f32x4 acc[2][8];
#pragma unroll
  for (int qt = 0; qt < 2; ++qt)
#pragma unroll
    for (int d = 0; d < 8; ++d) acc[qt][d] = f32x4{0.f, 0.f, 0.f, 0.f};
  float mrow[2][4], ssum[2][4];
#pragma unroll
  for (int qt = 0; qt < 2; ++qt)
#pragma unroll
    for (int r = 0; r < 4; ++r) { mrow[qt][r] = -1e30f; ssum[qt][r] = 0.f; }

  int jlo = i0b - WIN;
  if (jlo < 0) jlo = 0;
  jlo &= ~31;
  for (int j0 = jlo; j0 <= i0b; j0 += 32) {
    b16x8 kf[2][4];
#pragma unroll
    for (int jt = 0; jt < 2; ++jt) {
      const __bf16* krow = qp + (tb + j0 + jt * 16 + lo) * QKVN + DIM + kvh * HDIM + hi * 8;
#pragma unroll
      for (int c = 0; c < 4; ++c) kf[jt][c] = *(const b16x8*)(krow + c * 32);
    }
    f32x4 s[2][2];
#pragma unroll
    for (int qt = 0; qt < 2; ++qt)
#pragma unroll
      for (int jt = 0; jt < 2; ++jt) {
        s[qt][jt] = f32x4{0.f, 0.f, 0.f, 0.f};
#pragma unroll
        for (int c = 0; c < 4; ++c) s[qt][jt] = MFMA16(aq[qt][c], kf[jt][c], s[qt][jt]);
      }
#pragma unroll
    for (int qt = 0; qt < 2; ++qt) {
#pragma unroll
      for (int r = 0; r < 4; ++r) {
        const int i = i0b + qt * 16 + hi * 4 + r;
        float d0f = (float)(i - (j0 + lo));
        float d1f = (float)(i - (j0 + 16 + lo));
        float v0 = (d0f >= 0.f && d0f <= 512.f) ? (s[qt][0][r] * scale - slope * d0f) : -1e30f;
        float v1 = (d1f >= 0.f && d1f <= 512.f) ? (s[qt][1][r] * scale - slope * d1f) : -1e30f;
        float tm = fmaxf(v0, v1);
#pragma unroll
        for (int off = 1; off < 16; off <<= 1) tm = fmaxf(tm, __shfl_xor(tm, off));
        float mnew = fmaxf(mrow[qt][r], tm);
        float e0 = (v0 > -1e29f) ? __expf(v0 - mnew) : 0.f;
        float e1 = (v1 > -1e29f) ? __expf(v1 - mnew) : 0.f;
        float rs = e0 + e1;
#pragma unroll
        for (int off = 1; off < 16; off <<= 1) rs += __shfl_xor(rs, off);
        float corr = (mrow[qt][r] > -1e29f) ? __expf(mrow[qt][r] - mnew) : 0.f;
        ssum[qt][r] = ssum[qt][r] * corr + rs;
        mrow[qt][r] = mnew;
#pragma unroll
        for (int d = 0; d < 8; ++d) acc[qt][d][r] *= corr;
        p_lds[w][qt][(hi * 4 + r) * 32 + lo] = __float2bfloat16(e0);
        p_lds[w][qt][(hi * 4 + r) * 32 + 16 + lo] = __float2bfloat16(e1);
      }
    }
    b16x8 pa[2];
    pa[0] = *(const b16x8*)((const __bf16*)p_lds[w][0] + lo * 32 + hi * 8);
    pa[1] = *(const b16x8*)((const __bf16*)p_lds[w][1] + lo * 32 + hi * 8);
#pragma unroll
    for (int dh = 0; dh < 2; ++dh) {
      b16x8 bv[4];
#pragma unroll
      for (int dd = 0; dd < 4; ++dd) {
        int d = dh * 4 + dd;
        bv[dd] = *(const b16x8*)(vtp + (size_t)(d * 16 + lo) * CAPN + j0 + hi * 8);
      }
#pragma unroll
      for (int qt = 0; qt < 2; ++qt)
#pragma unroll
        for (int dd = 0; dd < 4; ++dd)
          acc[qt][dh * 4 + dd] = MFMA16(pa[qt], bv[dd], acc[qt][dh * 4 + dd]);
    }
  }
#pragma unroll
  for (int qt = 0; qt < 2; ++qt)
#pragma unroll
    for (int d = 0; d < 8; ++d)
#pragma unroll
      for (int r = 0; r < 4; ++r) {
        int row = i0b + qt * 16 + hi * 4 + r;
        attb[(tb + row) * DIM + h * HDIM + d * 16 + lo] =
            __float2bfloat16(acc[qt][d][r] / ssum[qt][r]);
      }
}

// ---------------- scale by top_w and scatter into pred ----------------
__global__ __launch_bounds__(256) void scatter_kernel(const float* __restrict__ lat,
                                                      const int* __restrict__ idxs,
                                                      const float* __restrict__ topw,
                                                      float* __restrict__ pred) {
  int tok = blockIdx.x;
  int b = tok >> 10, i = tok & 1023;
  int dst = idxs[b * CAPN + i];
  float wv = topw[b * CAPN + i];
  const float4* spv = (const float4*)(lat + (size_t)tok * DIM);
  float4* dp = (float4*)(pred + ((size_t)b * SEQ + dst) * DIM);
  int t = threadIdx.x;
  float4 v = spv[t];
  v.x *= wv; v.y *= wv; v.z *= wv; v.w *= wv;
  dp[t] = v;
  v = spv[t + 256];
  v.x *= wv; v.y *= wv; v.z *= wv; v.w *= wv;
  dp[t + 256] = v;
}

extern "C" void kernel_launch(void* const* d_in, const int* in_sizes, int n_in,
                              void* d_out, int out_size, void* d_ws, size_t ws_size,
                              hipStream_t stream) {
  const float* x        = (const float*)d_in[0];
  const float* router_w = (const float*)d_in[1];
  const float* norm1_w  = (const float*)d_in[2];
  const float* norm2_w  = (const float*)d_in[3];
  const float* qkv_w    = (const float*)d_in[4];
  const float* proj_w   = (const float*)d_in[5];
  const float* fc1_w    = (const float*)d_in[6];
  const float* fc2_w    = (const float*)d_in[7];

  float* pred   = (float*)d_out;                       // [NB,SEQ,DIM]
  float* rw_out = pred + (size_t)NB * SEQ * DIM;       // [NB,SEQ,1]
  float* dec    = rw_out + (size_t)NB * SEQ;           // [NB,SEQ,1]

  // workspace
  char* ws = (char*)d_ws;
  float* lat  = (float*)ws; ws += (size_t)MTOK * DIM * 4;       // 33.5 MB f32
  bf16* xn    = (bf16*)ws;  ws += (size_t)MTOK * DIM * 2;       // 16.8 MB
  bf16* qkvb  = (bf16*)ws;  ws += (size_t)MTOK * QKVN * 2;      // 25.2 MB
  bf16* attb  = (bf16*)ws;  ws += (size_t)MTOK * DIM * 2;       // 16.8 MB
  int* rank   = (int*)ws;   ws += (size_t)NB * SEQ * 4;
  int* idxs   = (int*)ws;   ws += (size_t)NB * CAPN * 4;
  float* topw = (float*)ws; ws += (size_t)NB * CAPN * 4;

  // scratch inside the pred output region (zeroed only at the very end)
  char* sp = (char*)pred;
  sp += (size_t)MTOK * (2 * DIM) * 2;                          // (hole, unused)
  bf16* wq = (bf16*)sp; sp += (size_t)QKVN * DIM * 2;          // 12.6 MB
  bf16* wp = (bf16*)sp; sp += (size_t)DIM * DIM * 2;           //  8.4 MB
  bf16* w1 = (bf16*)sp; sp += (size_t)(2 * DIM) * DIM * 2;     // 16.8 MB
  bf16* w2 = (bf16*)sp; sp += (size_t)DIM * DIM * 2;           //  8.4 MB
  bf16* vT = (bf16*)sp; sp += (size_t)NB * NKVH * HDIM * CAPN * 2;  // 4.2 MB

  // router + top-k (f32 exact path)
  router_kernel<<<NB * SEQ / 4, 256, 0, stream>>>(x, router_w, rw_out);
  hipMemsetAsync(rank, 0, (size_t)NB * SEQ * 4, stream);
  rankcnt_kernel<<<NB * 256, 256, 0, stream>>>(rw_out, rank);
  select_kernel<<<NB, 1024, 0, stream>>>(rank, rw_out, idxs, topw, dec);
  gather_kernel<<<MTOK, 256, 0, stream>>>(x, idxs, lat);

  for (int l = 0; l < NLAYER; ++l) {
    cast_kernel<<<(QKVN * DIM) / 1024, 256, 0, stream>>>(qkv_w + (size_t)l * QKVN * DIM, wq, QKVN * DIM);
    cast_kernel<<<(DIM * DIM) / 1024, 256, 0, stream>>>(proj_w + (size_t)l * DIM * DIM, wp, DIM * DIM);
    cast_fc1_kernel<<<2 * DIM, 256, 0, stream>>>(fc1_w + (size_t)l * 2 * DIM * DIM, w1);
    cast_kernel<<<(DIM * DIM) / 1024, 256, 0, stream>>>(fc2_w + (size_t)l * DIM * DIM, w2, DIM * DIM);

    rmsnorm_kernel<<<MTOK, 256, 0, stream>>>(lat, norm1_w + (size_t)l * DIM, xn);
    // qkv: M=4096 N=3072 -> grid 32*24 = 768
    gemm97<1><<<(MTOK / 128) * (QKVN / 128), 256, 0, stream>>>(
        xn, wq, nullptr, qkvb, vT, QKVN, DIM, QKVN / 128);
    attn_kernel<<<NB * NKVH * 32, 256, 0, stream>>>(qkvb, vT, attb);
    // proj: residual add into lat, grid 32*16 = 512
    gemm97<3><<<(MTOK / 128) * (DIM / 128), 256, 0, stream>>>(
        attb, wp, lat, nullptr, nullptr, DIM, DIM, DIM / 128);

    rmsnorm_kernel<<<MTOK, 256, 0, stream>>>(lat, norm2_w + (size_t)l * DIM, xn);
    // fc1 + fused SwiGLU: grid 32*32 = 1024, out attb [4096,2048]
    gemm97<2><<<(MTOK / 128) * (2 * DIM / 128), 256, 0, stream>>>(
        xn, w1, nullptr, attb, nullptr, 2 * DIM, DIM, 2 * DIM / 128);
    // fc2: residual add into lat, grid 512
    gemm97<3><<<(MTOK / 128) * (DIM / 128), 256, 0, stream>>>(
        attb, w2, lat, nullptr, nullptr, DIM, DIM, DIM / 128);
  }

  // finalize outputs: zero pred (erases scratch), then scatter lat * top_w
  hipMemsetAsync(pred, 0, (size_t)NB * SEQ * DIM * 4, stream);
  scatter_kernel<<<MTOK, 256, 0, stream>>>(lat, idxs, topw, pred);
}

// Round 9
// 1497.736 us; speedup vs baseline: 1.0826x; 1.0007x over previous
//
#include <hip/hip_runtime.h>
#include <hip/hip_bf16.h>

constexpr int NB = 4;
constexpr int SEQ = 4096;
constexpr int DIM = 2048;
constexpr int NLAYER = 4;
constexpr int NQH = 16;
constexpr int NKVH = 4;
constexpr int WIN = 512;
constexpr int HDIM = 128;
constexpr int CAPN = 1024;
constexpr int MTOK = NB * CAPN;                 // 4096 latent tokens
constexpr int QKVN = (NQH + 2 * NKVH) * HDIM;  // 3072
constexpr int VOFF = DIM + NKVH * HDIM;        // 2560, start of V cols
constexpr float EPSF = 1.1920928955078125e-07f;

typedef __hip_bfloat16 bf16;
typedef __bf16 b16x8 __attribute__((ext_vector_type(8)));
typedef __bf16 b16x4 __attribute__((ext_vector_type(4)));
typedef float f32x4 __attribute__((ext_vector_type(4)));

#define MFMA16(a, b, c) __builtin_amdgcn_mfma_f32_16x16x32_bf16((a), (b), (c), 0, 0, 0)

__device__ __forceinline__ void gload_lds16(const void* g, void* l) {
  __builtin_amdgcn_global_load_lds((__attribute__((address_space(1))) void*)(void*)g,
                                   (__attribute__((address_space(3))) void*)l, 16, 0, 0);
}

// ---------------- cast f32 -> bf16 ----------------
__global__ __launch_bounds__(256) void cast_kernel(const float* __restrict__ in,
                                                   bf16* __restrict__ out, int n) {
  int i = (blockIdx.x * 256 + threadIdx.x) * 4;
  if (i >= n) return;
  float4 v = *(const float4*)(in + i);
  b16x4 o;
  o[0] = (__bf16)v.x; o[1] = (__bf16)v.y; o[2] = (__bf16)v.z; o[3] = (__bf16)v.w;
  *(b16x4*)((__bf16*)out + i) = o;
}

// ------- cast fc1_w with row interleave: chunk c holds [16 a-rows | 16 gate] -------
__global__ __launch_bounds__(256) void cast_fc1_kernel(const float* __restrict__ in,
                                                       bf16* __restrict__ out) {
  int p = blockIdx.x;
  int chunk = p >> 5, w = p & 31;
  int L = (w < 16) ? (chunk * 16 + w) : (DIM + chunk * 16 + (w - 16));
  const float4* spv = (const float4*)(in + (size_t)L * DIM);
  __bf16* op = (__bf16*)out + (size_t)p * DIM;
  int t = threadIdx.x;
#pragma unroll
  for (int j = 0; j < 2; ++j) {
    float4 v = spv[t + j * 256];
    b16x4 o;
    o[0] = (__bf16)v.x; o[1] = (__bf16)v.y; o[2] = (__bf16)v.z; o[3] = (__bf16)v.w;
    *(b16x4*)(op + (t + j * 256) * 4) = o;
  }
}

// ---------------- router: rw = sigmoid(x @ w^T), all f32 ----------------
__global__ __launch_bounds__(256) void router_kernel(const float* __restrict__ x,
                                                     const float* __restrict__ rwt,
                                                     float* __restrict__ rw_out) {
  int tok = blockIdx.x * 4 + (threadIdx.x >> 6);
  int l = threadIdx.x & 63;
  const float* xr = x + (size_t)tok * DIM;
  float s = 0.f;
  for (int c = l; c < DIM; c += 64) s += xr[c] * rwt[c];
  for (int off = 32; off; off >>= 1) s += __shfl_down(s, off);
  if (l == 0) rw_out[tok] = 1.f / (1.f + expf(-s));
}

// ------- rank count, tiled: block (b, jc, ic) counts chunk-vs-chunk -------
__global__ __launch_bounds__(256) void rankcnt_kernel(const float* __restrict__ rw,
                                                      int* __restrict__ rank) {
  int blk = blockIdx.x;
  int ic = blk & 15, jc = (blk >> 4) & 15, b = blk >> 8;
  __shared__ float4 svi[64];
  int t = threadIdx.x;
  if (t < 64) svi[t] = ((const float4*)(rw + (size_t)b * SEQ + ic * 256))[t];
  __syncthreads();
  int j = jc * 256 + t;
  float vj = rw[(size_t)b * SEQ + j];
  int r = 0;
#pragma unroll 16
  for (int q = 0; q < 64; ++q) {
    float4 v = svi[q];
    int i = ic * 256 + q * 4;
    r += (v.x > vj || (v.x == vj && (i + 0) < j)) ? 1 : 0;
    r += (v.y > vj || (v.y == vj && (i + 1) < j)) ? 1 : 0;
    r += (v.z > vj || (v.z == vj && (i + 2) < j)) ? 1 : 0;
    r += (v.w > vj || (v.w == vj && (i + 3) < j)) ? 1 : 0;
  }
  atomicAdd(&rank[b * SEQ + j], r);
}

// -------- select: compact ascending-index selected; top_w quirk gather;
// also writes the `decisions` output --------
__global__ __launch_bounds__(1024) void select_kernel(const int* __restrict__ rank,
                                                      const float* __restrict__ rw,
                                                      int* __restrict__ idxs,
                                                      float* __restrict__ topw,
                                                      float* __restrict__ dec) {
  int b = blockIdx.x;
  int t = threadIdx.x;
  __shared__ int sr[SEQ];
  __shared__ int scnt[1024];
  for (int i = t; i < SEQ; i += 1024) sr[i] = rank[b * SEQ + i];
  __syncthreads();
  for (int i = t; i < SEQ; i += 1024) dec[(size_t)b * SEQ + i] = (sr[i] < CAPN) ? 1.0f : 0.0f;
  int c = 0;
#pragma unroll
  for (int k = 0; k < 4; ++k) c += (sr[t * 4 + k] < CAPN) ? 1 : 0;
  scnt[t] = c;
  __syncthreads();
  for (int off = 1; off < 1024; off <<= 1) {
    int v = scnt[t];
    int vm = (t >= off) ? scnt[t - off] : 0;
    __syncthreads();
    scnt[t] = v + vm;
    __syncthreads();
  }
  int pos = scnt[t] - c;  // exclusive prefix
  for (int k = 0; k < 4; ++k) {
    int j = t * 4 + k;
    int r = sr[j];
    if (r < CAPN) {
      idxs[b * CAPN + pos] = j;
      topw[b * CAPN + pos] = rw[(size_t)b * SEQ + r];
      pos++;
    }
  }
}

// ---------------- gather selected rows ----------------
__global__ __launch_bounds__(256) void gather_kernel(const float* __restrict__ x,
                                                     const int* __restrict__ idxs,
                                                     float* __restrict__ lat) {
  int tok = blockIdx.x;
  int b = tok >> 10, i = tok & 1023;
  int src = idxs[b * CAPN + i];
  const float4* spv = (const float4*)(x + ((size_t)b * SEQ + src) * DIM);
  float4* dp = (float4*)(lat + (size_t)tok * DIM);
  int t = threadIdx.x;
  dp[t] = spv[t];
  dp[t + 256] = spv[t + 256];
}

// ---------------- RMSNorm (f32 in, bf16 out) ----------------
__global__ __launch_bounds__(256) void rmsnorm_kernel(const float* __restrict__ in,
                                                      const float* __restrict__ w,
                                                      bf16* __restrict__ out) {
  int row = blockIdx.x;
  int t = threadIdx.x;
  const float4* spv = (const float4*)(in + (size_t)row * DIM);
  float4 v0 = spv[t], v1 = spv[t + 256];
  float ss = v0.x * v0.x + v0.y * v0.y + v0.z * v0.z + v0.w * v0.w +
             v1.x * v1.x + v1.y * v1.y + v1.z * v1.z + v1.w * v1.w;
  for (int off = 32; off; off >>= 1) ss += __shfl_down(ss, off);
  __shared__ float red[4];
  if ((t & 63) == 0) red[t >> 6] = ss;
  __syncthreads();
  float total = red[0] + red[1] + red[2] + red[3];
  float sc = rsqrtf(total * (1.0f / DIM) + EPSF);
  const float4* wp = (const float4*)w;
  float4 w0 = wp[t], w1 = wp[t + 256];
  __bf16* op = (__bf16*)out + (size_t)row * DIM;
  b16x4 o0, o1;
  o0[0] = (__bf16)(v0.x * w0.x * sc); o0[1] = (__bf16)(v0.y * w0.y * sc);
  o0[2] = (__bf16)(v0.z * w0.z * sc); o0[3] = (__bf16)(v0.w * w0.w * sc);
  o1[0] = (__bf16)(v1.x * w1.x * sc); o1[1] = (__bf16)(v1.y * w1.y * sc);
  o1[2] = (__bf16)(v1.z * w1.z * sc); o1[3] = (__bf16)(v1.w * w1.w * sc);
  *(b16x4*)(op + t * 4) = o0;
  *(b16x4*)(op + 1024 + t * 4) = o1;
}

// ============ m97-structure GEMM: 128x128 tile, BK=64, single-buffer ============
// 256 thr (4 waves 2x2), LDS 32 KB -> 3 blocks/CU. Mechanism: CROSS-BLOCK
// overlap (m114). MODE: 1 = bf16 + vT side-write; 2 = fused SwiGLU; 3 = f32 add.

__device__ __forceinline__ void stage97(const bf16* g, int K, int kt,
                                        bf16* tile, int tid) {
#pragma unroll
  for (int j = 0; j < 4; ++j) {
    int q = j * 4096 + tid * 16;
    int row = q >> 7;
    int sc = ((tid & 7) ^ (row & 7)) << 3;
    gload_lds16((const __bf16*)g + (size_t)row * K + kt * 64 + sc,
                (char*)tile + q);
  }
}

__device__ __forceinline__ b16x8 frag97(const bf16* buf, int row, int ks, int hi) {
  int co = (ks * 32 + hi * 8) ^ ((row & 7) << 3);
  return *(const b16x8*)((const __bf16*)buf + row * 64 + co);
}

template <int MODE>
__global__ __launch_bounds__(256, 3) void gemm97(const bf16* __restrict__ A,
                                                 const bf16* __restrict__ Bw,
                                                 float* __restrict__ Cf,
                                                 bf16* __restrict__ Cb,
                                                 bf16* __restrict__ vTout,
                                                 int N, int K, int nbn) {
  __shared__ __align__(16) bf16 sA[128 * 64];
  __shared__ __align__(16) bf16 sB[128 * 64];
  const int tid = threadIdx.x;
  const int w = tid >> 6, l = tid & 63;
  const int lo = l & 15, hi = l >> 4;
  const int wr = w >> 1, wc = w & 1;
  const int nwg = gridDim.x;
  int bid = blockIdx.x;
  bid = (bid & 7) * (nwg >> 3) + (bid >> 3);  // T1 XCD swizzle (nwg%8==0)
  const int bm = bid / nbn, bn = bid % nbn;
  const bf16* Ab = A + (size_t)bm * 128 * K;
  const bf16* Bb = Bw + (size_t)bn * 128 * K;
  const int nt = K >> 6;

  f32x4 acc[4][4];
#pragma unroll
  for (int i = 0; i < 4; ++i)
#pragma unroll
    for (int j = 0; j < 4; ++j) acc[i][j] = f32x4{0.f, 0.f, 0.f, 0.f};

  for (int t = 0; t < nt; ++t) {
    stage97(Ab, K, t, sA, tid);
    stage97(Bb, K, t, sB, tid);
    __syncthreads();
#pragma unroll
    for (int ks = 0; ks < 2; ++ks) {
      b16x8 af[4], bfm[4];
#pragma unroll
      for (int mi = 0; mi < 4; ++mi)
        af[mi] = frag97(sA, wr * 64 + mi * 16 + lo, ks, hi);
#pragma unroll
      for (int ni = 0; ni < 4; ++ni)
        bfm[ni] = frag97(sB, wc * 64 + ni * 16 + lo, ks, hi);
#pragma unroll
      for (int mi = 0; mi < 4; ++mi)
#pragma unroll
        for (int ni = 0; ni < 4; ++ni)
          acc[mi][ni] = MFMA16(af[mi], bfm[ni], acc[mi][ni]);
    }
    __syncthreads();
  }

  // epilogue
#pragma unroll
  for (int mi = 0; mi < 4; ++mi) {
    int row0 = bm * 128 + wr * 64 + mi * 16 + hi * 4;
    if constexpr (MODE == 2) {
#pragma unroll
      for (int j2 = 0; j2 < 2; ++j2) {
        int colL = bn * 64 + wc * 32 + j2 * 16 + lo;
#pragma unroll
        for (int r = 0; r < 4; ++r) {
          float a = acc[mi][2 * j2][r];
          float g = acc[mi][2 * j2 + 1][r];
          float s = g / (1.f + __expf(-g));
          Cb[(size_t)(row0 + r) * DIM + colL] = __float2bfloat16(a * s);
        }
      }
    } else {
#pragma unroll
      for (int ni = 0; ni < 4; ++ni) {
        int col = bn * 128 + wc * 64 + ni * 16 + lo;
#pragma unroll
        for (int r = 0; r < 4; ++r) {
          size_t idx = (size_t)(row0 + r) * N + col;
          float v = acc[mi][ni][r];
          if constexpr (MODE == 3) {
            Cf[idx] += v;
          } else {
            bf16 bv = __float2bfloat16(v);
            Cb[idx] = bv;
            if constexpr (MODE == 1) {
              if (col >= VOFF) {
                int cc = col - VOFF;
                int kvh = cc >> 7, d = cc & 127;
                int row = row0 + r;
                int bb = row >> 10, tk = row & 1023;
                vTout[((size_t)(bb * NKVH + kvh) * HDIM + d) * CAPN + tk] = bv;
              }
            }
          }
        }
      }
    }
  }
}

// ------------- GQA attention: 64-col K-steps, descending (diag-first) order,
// wave-uniform defer-max (THR=8), padded P-LDS (stride 72 -> 2-way banks) -------------
__global__ __launch_bounds__(256) void attn_kernel(const bf16* __restrict__ qkvb,
                                                   const bf16* __restrict__ vT,
                                                   bf16* __restrict__ attb) {
  const int blk = blockIdx.x;
  const int qc = blk & 31;
  const int kvh = (blk >> 5) & 3;
  const int b = blk >> 7;
  const int w = threadIdx.x >> 6, l = threadIdx.x & 63;
  const int lo = l & 15, hi = l >> 4;
  const int h = kvh * 4 + w;
  const float slope = exp2f(-0.5f * (float)(h + 1));
  const float scale = 0.08838834764831845f;  // 1/sqrt(128)
  __shared__ __align__(16) bf16 p_lds[4][2][16 * 72];  // stride 72 elems (144 B)
  const __bf16* qp = (const __bf16*)qkvb;
  const __bf16* vtp = (const __bf16*)vT + (size_t)(b * NKVH + kvh) * HDIM * CAPN;
  const size_t tb = (size_t)b * CAPN;
  const int i0b = qc * 32;

  b16x8 aq[2][4];
#pragma unroll
  for (int qt = 0; qt < 2; ++qt) {
    const __bf16* qrow = qp + (tb + i0b + qt * 16 + lo) * QKVN + h * HDIM + hi * 8;
#pragma unroll
    for (int c = 0; c < 4; ++c) aq[qt][c] = *(const b16x8*)(qrow + c * 32);
  }

  f32x4 acc[2][8];
#pragma unroll
  for (int qt = 0; qt < 2; ++qt)
#pragma unroll
    for (int d = 0; d < 8; ++d) acc[qt][d] = f32x4{0.f, 0.f, 0.f, 0.f};
  float mrow[2][4], ssum[2][4];
#pragma unroll
  for (int qt = 0; qt < 2; ++qt)
#pragma unroll
    for (int r = 0; r < 4; ++r) { mrow[qt][r] = -1e30f; ssum[qt][r] = 0.f; }

  // 64-aligned tile range: top tile contains col i0b+31; bottom contains window start
  const int Ttile = (i0b + 31) & ~63;
  int Btile = i0b - WIN;
  if (Btile < 0) Btile = 0;
  Btile &= ~63;

  for (int j0 = Ttile; j0 >= Btile; j0 -= 64) {
    // K fragments: 4 jt sub-tiles of 16 rows
    b16x8 kf[4][4];
#pragma unroll
    for (int jt = 0; jt < 4; ++jt) {
      const __bf16* krow = qp + (tb + j0 + jt * 16 + lo) * QKVN + DIM + kvh * HDIM + hi * 8;
#pragma unroll
      for (int c = 0; c < 4; ++c) kf[jt][c] = *(const b16x8*)(krow + c * 32);
    }
    f32x4 s[2][4];
#pragma unroll
    for (int qt = 0; qt < 2; ++qt)
#pragma unroll
      for (int jt = 0; jt < 4; ++jt) {
        s[qt][jt] = f32x4{0.f, 0.f, 0.f, 0.f};
#pragma unroll
        for (int c = 0; c < 4; ++c) s[qt][jt] = MFMA16(aq[qt][c], kf[jt][c], s[qt][jt]);
      }
    // mask + ALiBi + row-max (in-place into s); defer-max decision
    float tmv[2][4];
    int changed = 0;
#pragma unroll
    for (int qt = 0; qt < 2; ++qt) {
#pragma unroll
      for (int r = 0; r < 4; ++r) {
        const int i = i0b + qt * 16 + hi * 4 + r;
        float tm = -1e30f;
#pragma unroll
        for (int jt = 0; jt < 4; ++jt) {
          int d = i - (j0 + jt * 16 + lo);
          float v = (d >= 0 && d <= 512) ? (s[qt][jt][r] * scale - slope * (float)d)
                                         : -1e30f;
          s[qt][jt][r] = v;
          tm = fmaxf(tm, v);
        }
#pragma unroll
        for (int off = 1; off < 16; off <<= 1) tm = fmaxf(tm, __shfl_xor(tm, off));
        tmv[qt][r] = tm;
        changed |= (tm > mrow[qt][r] + 8.0f) ? 1 : 0;
      }
    }
    if (__any(changed)) {  // rare with diag-first order: rescale state
#pragma unroll
      for (int qt = 0; qt < 2; ++qt)
#pragma unroll
        for (int r = 0; r < 4; ++r) {
          float mnew = fmaxf(mrow[qt][r], tmv[qt][r]);
          float corr = (mrow[qt][r] > -1e29f) ? __expf(mrow[qt][r] - mnew) : 0.f;
          ssum[qt][r] *= corr;
#pragma unroll
          for (int d = 0; d < 8; ++d) acc[qt][d][r] *= corr;
          mrow[qt][r] = mnew;
        }
    }
    // P = exp(s - m) (bounded by e^8), row-sum, write to padded LDS
#pragma unroll
    for (int qt = 0; qt < 2; ++qt) {
#pragma unroll
      for (int r = 0; r < 4; ++r) {
        const float m = mrow[qt][r];
        float rs = 0.f;
#pragma unroll
        for (int jt = 0; jt < 4; ++jt) {
          float v = s[qt][jt][r];
          float p = (v > -1e29f) ? __expf(v - m) : 0.f;
          rs += p;
          p_lds[w][qt][(hi * 4 + r) * 72 + jt * 16 + lo] = __float2bfloat16(p);
        }
#pragma unroll
        for (int off = 1; off < 16; off <<= 1) rs += __shfl_xor(rs, off);
        ssum[qt][r] += rs;
      }
    }
    // PV over the 2 k-subtiles of 32
#pragma unroll
    for (int ks2 = 0; ks2 < 2; ++ks2) {
      b16x8 pa[2];
      pa[0] = *(const b16x8*)((const __bf16*)p_lds[w][0] + lo * 72 + ks2 * 32 + hi * 8);
      pa[1] = *(const b16x8*)((const __bf16*)p_lds[w][1] + lo * 72 + ks2 * 32 + hi * 8);
#pragma unroll
      for (int dh = 0; dh < 2; ++dh) {
        b16x8 bv[4];
#pragma unroll
        for (int dd = 0; dd < 4; ++dd) {
          int d = dh * 4 + dd;
          bv[dd] = *(const b16x8*)(vtp + (size_t)(d * 16 + lo) * CAPN + j0 + ks2 * 32 + hi * 8);
        }
#pragma unroll
        for (int qt = 0; qt < 2; ++qt)
#pragma unroll
          for (int dd = 0; dd < 4; ++dd)
            acc[qt][dh * 4 + dd] = MFMA16(pa[qt], bv[dd], acc[qt][dh * 4 + dd]);
      }
    }
  }
#pragma unroll
  for (int qt = 0; qt < 2; ++qt)
#pragma unroll
    for (int d = 0; d < 8; ++d)
#pragma unroll
      for (int r = 0; r < 4; ++r) {
        int row = i0b + qt * 16 + hi * 4 + r;
        attb[(tb + row) * DIM + h * HDIM + d * 16 + lo] =
            __float2bfloat16(acc[qt][d][r] / ssum[qt][r]);
      }
}

// ---------------- scale by top_w and scatter into pred ----------------
__global__ __launch_bounds__(256) void scatter_kernel(const float* __restrict__ lat,
                                                      const int* __restrict__ idxs,
                                                      const float* __restrict__ topw,
                                                      float* __restrict__ pred) {
  int tok = blockIdx.x;
  int b = tok >> 10, i = tok & 1023;
  int dst = idxs[b * CAPN + i];
  float wv = topw[b * CAPN + i];
  const float4* spv = (const float4*)(lat + (size_t)tok * DIM);
  float4* dp = (float4*)(pred + ((size_t)b * SEQ + dst) * DIM);
  int t = threadIdx.x;
  float4 v = spv[t];
  v.x *= wv; v.y *= wv; v.z *= wv; v.w *= wv;
  dp[t] = v;
  v = spv[t + 256];
  v.x *= wv; v.y *= wv; v.z *= wv; v.w *= wv;
  dp[t + 256] = v;
}

extern "C" void kernel_launch(void* const* d_in, const int* in_sizes, int n_in,
                              void* d_out, int out_size, void* d_ws, size_t ws_size,
                              hipStream_t stream) {
  const float* x        = (const float*)d_in[0];
  const float* router_w = (const float*)d_in[1];
  const float* norm1_w  = (const float*)d_in[2];
  const float* norm2_w  = (const float*)d_in[3];
  const float* qkv_w    = (const float*)d_in[4];
  const float* proj_w   = (const float*)d_in[5];
  const float* fc1_w    = (const float*)d_in[6];
  const float* fc2_w    = (const float*)d_in[7];

  float* pred   = (float*)d_out;                       // [NB,SEQ,DIM]
  float* rw_out = pred + (size_t)NB * SEQ * DIM;       // [NB,SEQ,1]
  float* dec    = rw_out + (size_t)NB * SEQ;           // [NB,SEQ,1]

  // workspace
  char* ws = (char*)d_ws;
  float* lat  = (float*)ws; ws += (size_t)MTOK * DIM * 4;       // 33.5 MB f32
  bf16* xn    = (bf16*)ws;  ws += (size_t)MTOK * DIM * 2;       // 16.8 MB
  bf16* qkvb  = (bf16*)ws;  ws += (size_t)MTOK * QKVN * 2;      // 25.2 MB
  bf16* attb  = (bf16*)ws;  ws += (size_t)MTOK * DIM * 2;       // 16.8 MB
  int* rank   = (int*)ws;   ws += (size_t)NB * SEQ * 4;
  int* idxs   = (int*)ws;   ws += (size_t)NB * CAPN * 4;
  float* topw = (float*)ws; ws += (size_t)NB * CAPN * 4;

  // scratch inside the pred output region (zeroed only at the very end)
  char* sp = (char*)pred;
  sp += (size_t)MTOK * (2 * DIM) * 2;                          // (hole, unused)
  bf16* wq = (bf16*)sp; sp += (size_t)QKVN * DIM * 2;          // 12.6 MB
  bf16* wp = (bf16*)sp; sp += (size_t)DIM * DIM * 2;           //  8.4 MB
  bf16* w1 = (bf16*)sp; sp += (size_t)(2 * DIM) * DIM * 2;     // 16.8 MB
  bf16* w2 = (bf16*)sp; sp += (size_t)DIM * DIM * 2;           //  8.4 MB
  bf16* vT = (bf16*)sp; sp += (size_t)NB * NKVH * HDIM * CAPN * 2;  // 4.2 MB

  // router + top-k (f32 exact path)
  router_kernel<<<NB * SEQ / 4, 256, 0, stream>>>(x, router_w, rw_out);
  hipMemsetAsync(rank, 0, (size_t)NB * SEQ * 4, stream);
  rankcnt_kernel<<<NB * 256, 256, 0, stream>>>(rw_out, rank);
  select_kernel<<<NB, 1024, 0, stream>>>(rank, rw_out, idxs, topw, dec);
  gather_kernel<<<MTOK, 256, 0, stream>>>(x, idxs, lat);

  for (int l = 0; l < NLAYER; ++l) {
    cast_kernel<<<(QKVN * DIM) / 1024, 256, 0, stream>>>(qkv_w + (size_t)l * QKVN * DIM, wq, QKVN * DIM);
    cast_kernel<<<(DIM * DIM) / 1024, 256, 0, stream>>>(proj_w + (size_t)l * DIM * DIM, wp, DIM * DIM);
    cast_fc1_kernel<<<2 * DIM, 256, 0, stream>>>(fc1_w + (size_t)l * 2 * DIM * DIM, w1);
    cast_kernel<<<(DIM * DIM) / 1024, 256, 0, stream>>>(fc2_w + (size_t)l * DIM * DIM, w2, DIM * DIM);

    rmsnorm_kernel<<<MTOK, 256, 0, stream>>>(lat, norm1_w + (size_t)l * DIM, xn);
    // qkv: M=4096 N=3072 -> grid 32*24 = 768
    gemm97<1><<<(MTOK / 128) * (QKVN / 128), 256, 0, stream>>>(
        xn, wq, nullptr, qkvb, vT, QKVN, DIM, QKVN / 128);
    attn_kernel<<<NB * NKVH * 32, 256, 0, stream>>>(qkvb, vT, attb);
    // proj: residual add into lat, grid 32*16 = 512
    gemm97<3><<<(MTOK / 128) * (DIM / 128), 256, 0, stream>>>(
        attb, wp, lat, nullptr, nullptr, DIM, DIM, DIM / 128);

    rmsnorm_kernel<<<MTOK, 256, 0, stream>>>(lat, norm2_w + (size_t)l * DIM, xn);
    // fc1 + fused SwiGLU: grid 32*32 = 1024, out attb [4096,2048]
    gemm97<2><<<(MTOK / 128) * (2 * DIM / 128), 256, 0, stream>>>(
        xn, w1, nullptr, attb, nullptr, 2 * DIM, DIM, 2 * DIM / 128);
    // fc2: residual add into lat, grid 512
    gemm97<3><<<(MTOK / 128) * (DIM / 128), 256, 0, stream>>>(
        attb, w2, lat, nullptr, nullptr, DIM, DIM, DIM / 128);
  }

  // finalize outputs: zero pred (erases scratch), then scatter lat * top_w
  hipMemsetAsync(pred, 0, (size_t)NB * SEQ * DIM * 4, stream);
  scatter_kernel<<<MTOK, 256, 0, stream>>>(lat, idxs, topw, pred);
}